// Round 11
// baseline (168.677 us; speedup 1.0000x reference)
//
#include <hip/hip_runtime.h>
#include <math.h>

#define N_NODES 20000
#define E_RAW   320000
#define E_TOT   (E_RAW + N_NODES)
#define IN_CH   256
#define HEADS   8
#define HID     32
#define HH      (HEADS*HID)   // 256
#define OUT_CH  40
#define NC2     48            // OUT_CH padded to 3x16
#define NEG     0.2f
#define CSTRIDE 64            // fixed bucket capacity per dst; P(deg>63) ~ 1e-16
#define DSTR    16            // deg counter stride (ints): 1 counter per 64B line

#define ZB_BLKS   79                       // zero deg: 79*256 >= 20000
#define HIST_BLKS ((E_TOT + 255) / 256)    // 1329 (standalone bucket build)
#define G1_BLKS   313                      // ceil(20000/64)
#define N_PAD     20032                    // padded rows for OOB-safe h2b staging

typedef __attribute__((ext_vector_type(8))) short  short8;
typedef __attribute__((ext_vector_type(4))) float  floatx4;

// bf16 helpers (bit-level, round-to-nearest-even; values are finite)
__device__ __forceinline__ unsigned short f2bf(float f) {
    unsigned int u = __float_as_uint(f);
    unsigned int r = (u + 0x7FFFu + ((u >> 16) & 1u)) >> 16;
    return (unsigned short)r;
}
__device__ __forceinline__ float bf2f(unsigned short h) {
    return __uint_as_float(((unsigned int)h) << 16);
}
__device__ __forceinline__ float lexp(float v) {
    v = (v > 0.f) ? v : NEG * v;
    return __expf(v);
}

// async global->LDS, 16B per lane. LDS dest is wave-uniform base + lane*16;
// global src is per-lane (we bake the XOR swizzle into the src address).
__device__ __forceinline__ void gload16(const void* g, void* l) {
    __builtin_amdgcn_global_load_lds(
        (const __attribute__((address_space(1))) void*)g,
        (__attribute__((address_space(3))) void*)l, 16, 0, 0);
}

// ---------------- setup: deg zero (64B-strided) + w1t/w2t prepack -----------

__global__ void setup_prep(const float* __restrict__ W1,
                           const float* __restrict__ W2,
                           unsigned short* __restrict__ w1t,
                           unsigned short* __restrict__ w2t,
                           int* __restrict__ deg) {
    int b = blockIdx.x;
    int t = threadIdx.x;
    if (b < ZB_BLKS) {
        int i = b * 256 + t;
        if (i < N_NODES) deg[i * DSTR] = 0;
    } else if (b < ZB_BLKS + HH) {
        int c = b - ZB_BLKS;
        w1t[c * IN_CH + t] = f2bf(W1[(size_t)t * HH + c]);
    } else {
        int c = b - ZB_BLKS - HH;       // 0..47
        w2t[c * HH + t] = (c < OUT_CH) ? f2bf(W2[(size_t)t * OUT_CH + c]) : (unsigned short)0;
    }
}

// ---------------- standalone single-pass bucket build -----------------------
// No LDS -> full occupancy (up to 8 blocks/CU); 5316 waves pipeline the
// atomic latency. deg padded to 1 counter / 64B line (16x less line-lock).

__global__ void scatter_build(const int* __restrict__ ei,
                              int* __restrict__ deg,
                              int* __restrict__ csr) {
    int e = blockIdx.x * 256 + threadIdx.x;
    if (e >= E_TOT) return;
    int s, d;
    if (e < E_RAW) { s = ei[e]; d = ei[E_RAW + e]; }
    else           { s = e - E_RAW; d = s; }
    int slot = atomicAdd(&deg[d * DSTR], 1);
    if (slot < CSTRIDE) csr[d * CSTRIDE + slot] = s;
}

// ---------------- Layer 1 GEMM (pure, 313 blocks) ---------------------------
// A tile: x (fp32) read directly, converted to bf16 in-register, ds_write with
// the same XOR swizzle the MFMA reads use. B: async gload16 (issued first, the
// DMA drains under the A-conversion VALU).
__global__ __launch_bounds__(256) void gemm1(const float* __restrict__ x,
                                             const unsigned short* __restrict__ w1t,
                                             const float* __restrict__ a1s,
                                             const float* __restrict__ a1d,
                                             unsigned short* __restrict__ h1b,
                                             float* __restrict__ as1,
                                             float* __restrict__ ad1) {
    __shared__ unsigned char Al[64 * 512];    // 32 KiB: [row][512B of K]
    __shared__ unsigned char Bl[256 * 128];   // 32 KiB: [col][128B K-chunk]
    int t = threadIdx.x;
    int wave = t >> 6, lane = t & 63;
    int ln = lane & 15, q = lane >> 4;
    int n0 = blockIdx.x * 64;
    const char* bbase = (const char*)w1t;

    // stage B chunk 0 via async DMA first (overlaps A conversion below)
    #pragma unroll
    for (int j = 0; j < 8; j++) {
        int R = (wave * 8 + j) * 1024;
        int o = R + lane * 16;
        int r = o >> 7;
        int cb = (o & 127) ^ ((r & 7) << 4);
        gload16(bbase + (size_t)r * 512 + cb, &Bl[R]);
    }

    // A tile: read x fp32, convert, swizzled ds_write (bit-identical to xb path)
    {
        int srow = t >> 4, scol = t & 15;     // 16 rows x 16 col-groups of 4
        #pragma unroll
        for (int pp = 0; pp < 4; pp++) {
            int row = srow + pp * 16;         // 0..63
            int n = n0 + row;
            #pragma unroll
            for (int kc = 0; kc < 4; kc++) {
                float4 v = (n < N_NODES)
                    ? *reinterpret_cast<const float4*>(&x[(size_t)n * IN_CH + kc * 64 + scol * 4])
                    : make_float4(0.f, 0.f, 0.f, 0.f);
                ushort4 pv;
                pv.x = f2bf(v.x); pv.y = f2bf(v.y); pv.z = f2bf(v.z); pv.w = f2bf(v.w);
                int bo = row * 512 + ((kc * 128 + scol * 8) ^ ((row & 7) << 4));
                *reinterpret_cast<ushort4*>(&Al[bo]) = pv;
            }
        }
    }
    __syncthreads();

    floatx4 acc[16];
    #pragma unroll
    for (int f = 0; f < 16; f++) acc[f] = (floatx4){0.f, 0.f, 0.f, 0.f};

    int xorv = (ln & 7) << 4;                 // row&7 == ln&7 for all frag rows

    for (int c = 0; c < 4; c++) {
        #pragma unroll
        for (int ks = 0; ks < 2; ks++) {
            int ao = (16 * wave + ln) * 512 + c * 128 + ((ks * 64 + q * 16) ^ xorv);
            short8 a = *reinterpret_cast<const short8*>(&Al[ao]);
            int bo0 = ln * 128 + ((ks * 64 + q * 16) ^ xorv);
            #pragma unroll
            for (int f = 0; f < 16; f++) {
                short8 bfr = *reinterpret_cast<const short8*>(&Bl[bo0 + f * 2048]);
                acc[f] = __builtin_amdgcn_mfma_f32_16x16x32_bf16(a, bfr, acc[f], 0, 0, 0);
            }
        }
        if (c < 3) {
            __syncthreads();                  // all waves done reading Bl
            #pragma unroll
            for (int j = 0; j < 8; j++) {
                int R = (wave * 8 + j) * 1024;
                int o = R + lane * 16;
                int r = o >> 7;
                int cb = (o & 127) ^ ((r & 7) << 4);
                gload16(bbase + (size_t)r * 512 + (c + 1) * 128 + cb, &Bl[R]);
            }
            __syncthreads();                  // drain + publish new chunk
        }
    }

    float Asr[16], Adr[16];
    #pragma unroll
    for (int f = 0; f < 16; f++) {
        Asr[f] = a1s[16 * f + ln];
        Adr[f] = a1d[16 * f + ln];
    }
    #pragma unroll
    for (int f = 0; f < 16; f++) {
        #pragma unroll
        for (int r = 0; r < 4; r++) {
            int n = n0 + 16 * wave + q * 4 + r;
            if (n < N_NODES)
                h1b[(size_t)n * HH + 16 * f + ln] = f2bf(acc[f][r]);
        }
    }
    #pragma unroll
    for (int lh = 0; lh < 8; lh++) {
        #pragma unroll
        for (int r = 0; r < 4; r++) {
            float ps = acc[2*lh][r] * Asr[2*lh] + acc[2*lh+1][r] * Asr[2*lh+1];
            float pd = acc[2*lh][r] * Adr[2*lh] + acc[2*lh+1][r] * Adr[2*lh+1];
            ps += __shfl_xor(ps, 1); ps += __shfl_xor(ps, 2);
            ps += __shfl_xor(ps, 4); ps += __shfl_xor(ps, 8);
            pd += __shfl_xor(pd, 1); pd += __shfl_xor(pd, 2);
            pd += __shfl_xor(pd, 4); pd += __shfl_xor(pd, 8);
            int n = n0 + 16 * wave + q * 4 + r;
            if (ln == 0 && n < N_NODES) {
                as1[n * HEADS + lh] = ps;
                ad1[n * HEADS + lh] = pd;
            }
        }
    }
}

// ---------------- Layer 1 attention + aggregate + bias + ELU ----------------
// ONE WAVE PER NODE (20000 waves -- gather is latency-bound, needs max TLP).

__global__ __launch_bounds__(256) void aggr1(const unsigned short* __restrict__ h1b,
                                             const float* __restrict__ as1,
                                             const float* __restrict__ ad1,
                                             const float* __restrict__ b1,
                                             const int* __restrict__ degv,
                                             const int* __restrict__ csr,
                                             unsigned short* __restrict__ h2b) {
    int d = blockIdx.x * 4 + (threadIdx.x >> 6);
    int lane = threadIdx.x & 63;
    int h = lane >> 3;
    int c4 = lane * 4;
    int start = d * CSTRIDE;
    int deg = degv[d * DSTR];
    deg = (deg > CSTRIDE) ? CSTRIDE : deg;
    float adv = ad1[d * HEADS + h];

    float a0 = 0.f, a1 = 0.f, a2 = 0.f, a3 = 0.f, den = 0.f;
    int jj = 0;
    for (; jj + 8 <= deg; jj += 8) {
        int s[8];
        #pragma unroll
        for (int i = 0; i < 8; i++) s[i] = csr[start + jj + i];
        float e[8];
        #pragma unroll
        for (int i = 0; i < 8; i++) e[i] = as1[s[i] * HEADS + h];
        ushort4 pv[8];
        #pragma unroll
        for (int i = 0; i < 8; i++)
            pv[i] = *reinterpret_cast<const ushort4*>(&h1b[(size_t)s[i] * HH + c4]);
        #pragma unroll
        for (int i = 0; i < 8; i++) {
            float w = lexp(e[i] + adv);
            den += w;
            a0 = fmaf(bf2f(pv[i].x), w, a0);
            a1 = fmaf(bf2f(pv[i].y), w, a1);
            a2 = fmaf(bf2f(pv[i].z), w, a2);
            a3 = fmaf(bf2f(pv[i].w), w, a3);
        }
    }
    for (; jj < deg; jj++) {
        int s = csr[start + jj];
        float w = lexp(as1[s * HEADS + h] + adv);
        den += w;
        ushort4 pv = *reinterpret_cast<const ushort4*>(&h1b[(size_t)s * HH + c4]);
        a0 = fmaf(bf2f(pv.x), w, a0);
        a1 = fmaf(bf2f(pv.y), w, a1);
        a2 = fmaf(bf2f(pv.z), w, a2);
        a3 = fmaf(bf2f(pv.w), w, a3);
    }
    float inv = 1.0f / (den + 1e-16f);
    float4 bv = *reinterpret_cast<const float4*>(&b1[c4]);
    float r0 = a0 * inv + bv.x;
    float r1 = a1 * inv + bv.y;
    float r2 = a2 * inv + bv.z;
    float r3 = a3 * inv + bv.w;
    r0 = (r0 > 0.f) ? r0 : (__expf(r0) - 1.f);
    r1 = (r1 > 0.f) ? r1 : (__expf(r1) - 1.f);
    r2 = (r2 > 0.f) ? r2 : (__expf(r2) - 1.f);
    r3 = (r3 > 0.f) ? r3 : (__expf(r3) - 1.f);
    ushort4 ov;
    ov.x = f2bf(r0); ov.y = f2bf(r1); ov.z = f2bf(r2); ov.w = f2bf(r3);
    *reinterpret_cast<ushort4*>(&h2b[(size_t)d * HH + c4]) = ov;
}

// ---------------- Layer 2 GEMM: fully async-LDS staged, single phase --------

__global__ __launch_bounds__(256) void gemm2(const unsigned short* __restrict__ h2b,
                                             const unsigned short* __restrict__ w2t,
                                             const float* __restrict__ a2s,
                                             const float* __restrict__ a2d,
                                             unsigned short* __restrict__ h3b,
                                             float* __restrict__ as2,
                                             float* __restrict__ ad2) {
    __shared__ unsigned char Al[64 * 512];   // 32 KiB
    __shared__ unsigned char Bl[NC2 * 512];  // 24 KiB
    int t = threadIdx.x;
    int wave = t >> 6, lane = t & 63;
    int ln = lane & 15, q = lane >> 4;
    int n0 = blockIdx.x * 64;
    const char* abase = (const char*)h2b + (size_t)n0 * 512;
    const char* bbase = (const char*)w2t;

    #pragma unroll
    for (int j = 0; j < 8; j++) {
        int R = (wave * 8 + j) * 1024;
        int o = R + lane * 16;
        int r = o >> 9;
        int cb = (o & 511) ^ ((r & 7) << 4);
        gload16(abase + (size_t)r * 512 + cb, &Al[R]);
    }
    #pragma unroll
    for (int j = 0; j < 6; j++) {
        int R = (wave * 6 + j) * 1024;
        int o = R + lane * 16;
        int r = o >> 9;
        int cb = (o & 511) ^ ((r & 7) << 4);
        gload16(bbase + (size_t)r * 512 + cb, &Bl[R]);
    }
    __syncthreads();

    floatx4 acc[3];
    #pragma unroll
    for (int f = 0; f < 3; f++) acc[f] = (floatx4){0.f, 0.f, 0.f, 0.f};

    int xorv = (ln & 7) << 4;

    #pragma unroll
    for (int kf = 0; kf < 8; kf++) {
        int ao = ((16 * wave + ln) * 512 + kf * 64 + q * 16) ^ xorv;
        short8 a = *reinterpret_cast<const short8*>(&Al[ao]);
        int bo0 = (ln * 512 + kf * 64 + q * 16) ^ xorv;
        #pragma unroll
        for (int f = 0; f < 3; f++) {
            short8 bfr = *reinterpret_cast<const short8*>(&Bl[bo0 + f * 8192]);
            acc[f] = __builtin_amdgcn_mfma_f32_16x16x32_bf16(a, bfr, acc[f], 0, 0, 0);
        }
    }

    float a2sv[3], a2dv[3];
    #pragma unroll
    for (int f = 0; f < 3; f++) {
        int c = 16 * f + ln;
        a2sv[f] = (c < OUT_CH) ? a2s[c] : 0.f;
        a2dv[f] = (c < OUT_CH) ? a2d[c] : 0.f;
    }
    #pragma unroll
    for (int r = 0; r < 4; r++) {
        int n = n0 + 16 * wave + q * 4 + r;
        float ps = acc[0][r] * a2sv[0] + acc[1][r] * a2sv[1] + acc[2][r] * a2sv[2];
        float pd = acc[0][r] * a2dv[0] + acc[1][r] * a2dv[1] + acc[2][r] * a2dv[2];
        ps += __shfl_xor(ps, 1); ps += __shfl_xor(ps, 2);
        ps += __shfl_xor(ps, 4); ps += __shfl_xor(ps, 8);
        pd += __shfl_xor(pd, 1); pd += __shfl_xor(pd, 2);
        pd += __shfl_xor(pd, 4); pd += __shfl_xor(pd, 8);
        if (n < N_NODES) {
            #pragma unroll
            for (int f = 0; f < 3; f++) {
                int c = 16 * f + ln;
                if (c < OUT_CH)
                    h3b[(size_t)n * OUT_CH + c] = f2bf(acc[f][r]);
            }
            if (ln == 0) { as2[n] = ps; ad2[n] = pd; }
        }
    }
}

// ---------------- Layer 2 attention + aggregate + log_softmax ----------------

__global__ __launch_bounds__(256) void aggr2(const unsigned short* __restrict__ h3b,
                                             const float* __restrict__ as2,
                                             const float* __restrict__ ad2,
                                             const float* __restrict__ b2,
                                             const int* __restrict__ degv,
                                             const int* __restrict__ csr,
                                             float* __restrict__ out) {
    int d = blockIdx.x * 4 + (threadIdx.x >> 6);
    int lane = threadIdx.x & 63;
    int start = d * CSTRIDE;
    int deg = degv[d * DSTR];
    deg = (deg > CSTRIDE) ? CSTRIDE : deg;
    float adv = ad2[d];
    bool ok = (lane < OUT_CH);
    int cl = ok ? lane : 0;

    float acc = 0.f, den = 0.f;
    int jj = 0;
    for (; jj + 8 <= deg; jj += 8) {
        int s[8];
        #pragma unroll
        for (int i = 0; i < 8; i++) s[i] = csr[start + jj + i];
        float e[8];
        #pragma unroll
        for (int i = 0; i < 8; i++) e[i] = as2[s[i]];
        unsigned short qv[8];
        #pragma unroll
        for (int i = 0; i < 8; i++) qv[i] = h3b[(size_t)s[i] * OUT_CH + cl];
        #pragma unroll
        for (int i = 0; i < 8; i++) {
            float w = lexp(e[i] + adv);
            den += w;
            acc = fmaf(bf2f(qv[i]), w, acc);
        }
    }
    for (; jj < deg; jj++) {
        int s = csr[start + jj];
        float w = lexp(as2[s] + adv);
        den += w;
        acc = fmaf(bf2f(h3b[(size_t)s * OUT_CH + cl]), w, acc);
    }

    float r = ok ? (acc / (den + 1e-16f) + b2[lane]) : -1e30f;
    float mx = r;
    #pragma unroll
    for (int off = 32; off >= 1; off >>= 1) mx = fmaxf(mx, __shfl_xor(mx, off));
    float ex = ok ? __expf(r - mx) : 0.f;
    float se = ex;
    #pragma unroll
    for (int off = 32; off >= 1; off >>= 1) se += __shfl_xor(se, off);
    if (ok) out[(size_t)d * OUT_CH + lane] = r - mx - __logf(se);
}

// ---------------- host launcher ----------------
// 6 dispatches: setup_prep, scatter_build (LDS-free, full occupancy),
// gemm1 (pure), aggr1, gemm2, aggr2.

extern "C" void kernel_launch(void* const* d_in, const int* in_sizes, int n_in,
                              void* d_out, int out_size, void* d_ws, size_t ws_size,
                              hipStream_t stream) {
    const float* x   = (const float*)d_in[0];
    const int*   ei  = (const int*)  d_in[1];
    const float* W1  = (const float*)d_in[2];
    const float* a1s = (const float*)d_in[3];
    const float* a1d = (const float*)d_in[4];
    const float* b1  = (const float*)d_in[5];
    const float* W2  = (const float*)d_in[6];
    const float* a2s = (const float*)d_in[7];
    const float* a2d = (const float*)d_in[8];
    const float* b2  = (const float*)d_in[9];
    float* out = (float*)d_out;

    char* p = (char*)d_ws;
    auto alloc = [&](size_t bytes) {
        char* r = p;
        p += (bytes + 255) & ~(size_t)255;
        return r;
    };
    unsigned short* h1b = (unsigned short*)alloc((size_t)N_NODES * HH * 2);
    unsigned short* h2b = (unsigned short*)alloc((size_t)N_PAD * HH * 2);
    unsigned short* h3b = (unsigned short*)alloc((size_t)N_NODES * OUT_CH * 2);
    unsigned short* w1t = (unsigned short*)alloc((size_t)IN_CH * HH * 2);
    unsigned short* w2t = (unsigned short*)alloc((size_t)NC2 * HH * 2);
    float* as1  = (float*)alloc((size_t)N_NODES * HEADS * 4);
    float* ad1  = (float*)alloc((size_t)N_NODES * HEADS * 4);
    float* as2v = (float*)alloc((size_t)N_NODES * 4);
    float* ad2v = (float*)alloc((size_t)N_NODES * 4);
    int* deg    = (int*)alloc((size_t)N_NODES * DSTR * 4);   // 1 counter / 64B line
    int* csr    = (int*)alloc((size_t)N_NODES * CSTRIDE * 4);

    setup_prep<<<ZB_BLKS + HH + NC2, 256, 0, stream>>>(W1, W2, w1t, w2t, deg);
    scatter_build<<<HIST_BLKS, 256, 0, stream>>>(ei, deg, csr);
    gemm1<<<G1_BLKS, 256, 0, stream>>>(x, w1t, a1s, a1d, h1b, as1, ad1);
    aggr1<<<N_NODES / 4, 256, 0, stream>>>(h1b, as1, ad1, b1, deg, csr, h2b);
    gemm2<<<313, 256, 0, stream>>>(h2b, w2t, a2s, a2d, h3b, as2v, ad2v);
    aggr2<<<N_NODES / 4, 256, 0, stream>>>(h3b, as2v, ad2v, b2, deg, csr, out);
}

// Round 12
// 161.313 us; speedup vs baseline: 1.0457x; 1.0457x over previous
//
#include <hip/hip_runtime.h>
#include <math.h>

#define N_NODES 20000
#define E_RAW   320000
#define E_TOT   (E_RAW + N_NODES)
#define IN_CH   256
#define HEADS   8
#define HID     32
#define HH      (HEADS*HID)   // 256
#define OUT_CH  40
#define NC2     48            // OUT_CH padded to 3x16
#define NEG     0.2f
#define CSTRIDE 64            // fixed bucket capacity per dst; P(deg>63) ~ 1e-16

#define ZB_BLKS   79                       // zero deg: 79*256 >= 20000
#define XW_BLKS   2500                     // x L3-warm blocks (8 rows each)
#define HIST_BLKS ((E_TOT + 255) / 256)    // 1329 (bucket build, in gemm1 tail)
#define G1_BLKS   625                      // 20000 / 32-row tiles (exact)
#define N_PAD     20032                    // padded rows for OOB-safe h2b staging

typedef __attribute__((ext_vector_type(8))) short  short8;
typedef __attribute__((ext_vector_type(4))) float  floatx4;

// bf16 helpers (bit-level, round-to-nearest-even; values are finite)
__device__ __forceinline__ unsigned short f2bf(float f) {
    unsigned int u = __float_as_uint(f);
    unsigned int r = (u + 0x7FFFu + ((u >> 16) & 1u)) >> 16;
    return (unsigned short)r;
}
__device__ __forceinline__ float bf2f(unsigned short h) {
    return __uint_as_float(((unsigned int)h) << 16);
}
__device__ __forceinline__ float lexp(float v) {
    v = (v > 0.f) ? v : NEG * v;
    return __expf(v);
}

// async global->LDS, 16B per lane. LDS dest is wave-uniform base + lane*16;
// global src is per-lane (we bake the XOR swizzle into the src address).
__device__ __forceinline__ void gload16(const void* g, void* l) {
    __builtin_amdgcn_global_load_lds(
        (const __attribute__((address_space(1))) void*)g,
        (__attribute__((address_space(3))) void*)l, 16, 0, 0);
}

// ---------------- setup: deg zero + w1t/w2t prepack + x L3-warm -------------
// The harness's 256MiB workspace fill flushes L3 every iteration; warming x
// here (reads overlap setup's latency-idle waves) turns gemm1's A-stage
// misses into L3/L2 hits.

__global__ void setup_prep(const float* __restrict__ x,
                           const float* __restrict__ W1,
                           const float* __restrict__ W2,
                           unsigned short* __restrict__ w1t,
                           unsigned short* __restrict__ w2t,
                           int* __restrict__ deg) {
    int b = blockIdx.x;
    int t = threadIdx.x;
    if (b < ZB_BLKS) {
        int i = b * 256 + t;
        if (i < N_NODES) deg[i] = 0;
    } else if (b < ZB_BLKS + HH) {
        int c = b - ZB_BLKS;
        w1t[c * IN_CH + t] = f2bf(W1[(size_t)t * HH + c]);
    } else if (b < ZB_BLKS + HH + NC2) {
        int c = b - ZB_BLKS - HH;       // 0..47
        w2t[c * HH + t] = (c < OUT_CH) ? f2bf(W2[(size_t)t * OUT_CH + c]) : (unsigned short)0;
    } else {
        int bb = b - (ZB_BLKS + HH + NC2);
        int n = bb * 8 + (t >> 5);
        int c0 = (t & 31) * 8;
        const float4* src = reinterpret_cast<const float4*>(&x[(size_t)n * IN_CH + c0]);
        float4 v0 = src[0], v1 = src[1];
        float s = v0.x + v0.y + v0.z + v0.w + v1.x + v1.y + v1.z + v1.w;
        asm volatile("" :: "v"(s));     // keep warm-reads alive (no DCE)
    }
}

// ---------------- Layer 1 GEMM (32-row tiles) + fused bucket build ----------
// 625 gemm blocks + 1329 scatter blocks. LDS 48KB -> 3 blocks/CU (~10 waves/CU
// vs R10's ~5): cold-miss latency now hidden by TLP.
// Wave w: row-group rg=w&1 (16 rows), col-group cg=w>>1 (8 of 16 col-frags).
__global__ __launch_bounds__(256) void gemm1(const float* __restrict__ x,
                                             const unsigned short* __restrict__ w1t,
                                             const float* __restrict__ a1s,
                                             const float* __restrict__ a1d,
                                             unsigned short* __restrict__ h1b,
                                             float* __restrict__ as1,
                                             float* __restrict__ ad1,
                                             const int* __restrict__ ei,
                                             int* __restrict__ deg,
                                             int* __restrict__ csr) {
    __shared__ unsigned char Al[32 * 512];    // 16 KiB: [row][512B of K]
    __shared__ unsigned char Bl[256 * 128];   // 32 KiB: [col][128B K-chunk]
    int t = threadIdx.x;

    if (blockIdx.x >= G1_BLKS) {              // fused bucket build (hist+scatter)
        int e = (blockIdx.x - G1_BLKS) * 256 + t;
        if (e < E_TOT) {
            int s, d;
            if (e < E_RAW) { s = ei[e]; d = ei[E_RAW + e]; }
            else           { s = e - E_RAW; d = s; }
            int slot = atomicAdd(&deg[d], 1);
            if (slot < CSTRIDE) csr[d * CSTRIDE + slot] = s;
        }
        return;
    }

    int wave = t >> 6, lane = t & 63;
    int ln = lane & 15, q = lane >> 4;
    int rg = wave & 1, cg = wave >> 1;
    int n0 = blockIdx.x * 32;
    const char* bbase = (const char*)w1t;

    // stage B chunk 0 via async DMA first (drains under A conversion)
    #pragma unroll
    for (int j = 0; j < 8; j++) {
        int R = (wave * 8 + j) * 1024;
        int o = R + lane * 16;
        int r = o >> 7;
        int cb = (o & 127) ^ ((r & 7) << 4);
        gload16(bbase + (size_t)r * 512 + cb, &Bl[R]);
    }

    // A tile: 32 rows x 256 fp32 -> bf16, swizzled ds_write (8 rows/thread-grp)
    {
        int row = t >> 3;                     // 0..31
        int cseg = (t & 7) * 32;              // 32 floats per thread
        int n = n0 + row;                     // always < N_NODES (exact tiling)
        #pragma unroll
        for (int kc = 0; kc < 8; kc++) {
            float4 v = *reinterpret_cast<const float4*>(&x[(size_t)n * IN_CH + cseg + kc * 4]);
            ushort4 pv;
            pv.x = f2bf(v.x); pv.y = f2bf(v.y); pv.z = f2bf(v.z); pv.w = f2bf(v.w);
            int bo = row * 512 + ((cseg * 2 + kc * 8) ^ ((row & 7) << 4));
            *reinterpret_cast<ushort4*>(&Al[bo]) = pv;
        }
    }
    __syncthreads();

    floatx4 acc[8];
    #pragma unroll
    for (int f = 0; f < 8; f++) acc[f] = (floatx4){0.f, 0.f, 0.f, 0.f};

    int xorv = (ln & 7) << 4;                 // row&7 == ln&7 for all frag rows

    for (int c = 0; c < 4; c++) {
        #pragma unroll
        for (int ks = 0; ks < 2; ks++) {
            int ao = (16 * rg + ln) * 512 + c * 128 + ((ks * 64 + q * 16) ^ xorv);
            short8 a = *reinterpret_cast<const short8*>(&Al[ao]);
            int bo0 = cg * 16384 + ln * 128 + ((ks * 64 + q * 16) ^ xorv);
            #pragma unroll
            for (int f = 0; f < 8; f++) {
                short8 bfr = *reinterpret_cast<const short8*>(&Bl[bo0 + f * 2048]);
                acc[f] = __builtin_amdgcn_mfma_f32_16x16x32_bf16(a, bfr, acc[f], 0, 0, 0);
            }
        }
        if (c < 3) {
            __syncthreads();                  // all waves done reading Bl
            #pragma unroll
            for (int j = 0; j < 8; j++) {
                int R = (wave * 8 + j) * 1024;
                int o = R + lane * 16;
                int r = o >> 7;
                int cb = (o & 127) ^ ((r & 7) << 4);
                gload16(bbase + (size_t)r * 512 + (c + 1) * 128 + cb, &Bl[R]);
            }
            __syncthreads();                  // drain + publish new chunk
        }
    }

    float Asr[8], Adr[8];
    #pragma unroll
    for (int f = 0; f < 8; f++) {
        Asr[f] = a1s[cg * 128 + 16 * f + ln];
        Adr[f] = a1d[cg * 128 + 16 * f + ln];
    }
    #pragma unroll
    for (int f = 0; f < 8; f++) {
        #pragma unroll
        for (int r = 0; r < 4; r++) {
            int n = n0 + 16 * rg + q * 4 + r;
            h1b[(size_t)n * HH + cg * 128 + 16 * f + ln] = f2bf(acc[f][r]);
        }
    }
    #pragma unroll
    for (int lh = 0; lh < 4; lh++) {          // wave covers heads 4cg..4cg+3
        #pragma unroll
        for (int r = 0; r < 4; r++) {
            float ps = acc[2*lh][r] * Asr[2*lh] + acc[2*lh+1][r] * Asr[2*lh+1];
            float pd = acc[2*lh][r] * Adr[2*lh] + acc[2*lh+1][r] * Adr[2*lh+1];
            ps += __shfl_xor(ps, 1); ps += __shfl_xor(ps, 2);
            ps += __shfl_xor(ps, 4); ps += __shfl_xor(ps, 8);
            pd += __shfl_xor(pd, 1); pd += __shfl_xor(pd, 2);
            pd += __shfl_xor(pd, 4); pd += __shfl_xor(pd, 8);
            int n = n0 + 16 * rg + q * 4 + r;
            if (ln == 0) {
                as1[n * HEADS + cg * 4 + lh] = ps;
                ad1[n * HEADS + cg * 4 + lh] = pd;
            }
        }
    }
}

// ---------------- Layer 1 attention + aggregate + bias + ELU ----------------
// ONE WAVE PER NODE (20000 waves -- gather is latency-bound, needs max TLP).

__global__ __launch_bounds__(256) void aggr1(const unsigned short* __restrict__ h1b,
                                             const float* __restrict__ as1,
                                             const float* __restrict__ ad1,
                                             const float* __restrict__ b1,
                                             const int* __restrict__ degv,
                                             const int* __restrict__ csr,
                                             unsigned short* __restrict__ h2b) {
    int d = blockIdx.x * 4 + (threadIdx.x >> 6);
    int lane = threadIdx.x & 63;
    int h = lane >> 3;
    int c4 = lane * 4;
    int start = d * CSTRIDE;
    int deg = degv[d];
    deg = (deg > CSTRIDE) ? CSTRIDE : deg;
    float adv = ad1[d * HEADS + h];

    float a0 = 0.f, a1 = 0.f, a2 = 0.f, a3 = 0.f, den = 0.f;
    int jj = 0;
    for (; jj + 8 <= deg; jj += 8) {
        int s[8];
        #pragma unroll
        for (int i = 0; i < 8; i++) s[i] = csr[start + jj + i];
        float e[8];
        #pragma unroll
        for (int i = 0; i < 8; i++) e[i] = as1[s[i] * HEADS + h];
        ushort4 pv[8];
        #pragma unroll
        for (int i = 0; i < 8; i++)
            pv[i] = *reinterpret_cast<const ushort4*>(&h1b[(size_t)s[i] * HH + c4]);
        #pragma unroll
        for (int i = 0; i < 8; i++) {
            float w = lexp(e[i] + adv);
            den += w;
            a0 = fmaf(bf2f(pv[i].x), w, a0);
            a1 = fmaf(bf2f(pv[i].y), w, a1);
            a2 = fmaf(bf2f(pv[i].z), w, a2);
            a3 = fmaf(bf2f(pv[i].w), w, a3);
        }
    }
    for (; jj < deg; jj++) {
        int s = csr[start + jj];
        float w = lexp(as1[s * HEADS + h] + adv);
        den += w;
        ushort4 pv = *reinterpret_cast<const ushort4*>(&h1b[(size_t)s * HH + c4]);
        a0 = fmaf(bf2f(pv.x), w, a0);
        a1 = fmaf(bf2f(pv.y), w, a1);
        a2 = fmaf(bf2f(pv.z), w, a2);
        a3 = fmaf(bf2f(pv.w), w, a3);
    }
    float inv = 1.0f / (den + 1e-16f);
    float4 bv = *reinterpret_cast<const float4*>(&b1[c4]);
    float r0 = a0 * inv + bv.x;
    float r1 = a1 * inv + bv.y;
    float r2 = a2 * inv + bv.z;
    float r3 = a3 * inv + bv.w;
    r0 = (r0 > 0.f) ? r0 : (__expf(r0) - 1.f);
    r1 = (r1 > 0.f) ? r1 : (__expf(r1) - 1.f);
    r2 = (r2 > 0.f) ? r2 : (__expf(r2) - 1.f);
    r3 = (r3 > 0.f) ? r3 : (__expf(r3) - 1.f);
    ushort4 ov;
    ov.x = f2bf(r0); ov.y = f2bf(r1); ov.z = f2bf(r2); ov.w = f2bf(r3);
    *reinterpret_cast<ushort4*>(&h2b[(size_t)d * HH + c4]) = ov;
}

// ---------------- Layer 2 GEMM: fully async-LDS staged, single phase --------

__global__ __launch_bounds__(256) void gemm2(const unsigned short* __restrict__ h2b,
                                             const unsigned short* __restrict__ w2t,
                                             const float* __restrict__ a2s,
                                             const float* __restrict__ a2d,
                                             unsigned short* __restrict__ h3b,
                                             float* __restrict__ as2,
                                             float* __restrict__ ad2) {
    __shared__ unsigned char Al[64 * 512];   // 32 KiB
    __shared__ unsigned char Bl[NC2 * 512];  // 24 KiB
    int t = threadIdx.x;
    int wave = t >> 6, lane = t & 63;
    int ln = lane & 15, q = lane >> 4;
    int n0 = blockIdx.x * 64;
    const char* abase = (const char*)h2b + (size_t)n0 * 512;
    const char* bbase = (const char*)w2t;

    #pragma unroll
    for (int j = 0; j < 8; j++) {
        int R = (wave * 8 + j) * 1024;
        int o = R + lane * 16;
        int r = o >> 9;
        int cb = (o & 511) ^ ((r & 7) << 4);
        gload16(abase + (size_t)r * 512 + cb, &Al[R]);
    }
    #pragma unroll
    for (int j = 0; j < 6; j++) {
        int R = (wave * 6 + j) * 1024;
        int o = R + lane * 16;
        int r = o >> 9;
        int cb = (o & 511) ^ ((r & 7) << 4);
        gload16(bbase + (size_t)r * 512 + cb, &Bl[R]);
    }
    __syncthreads();

    floatx4 acc[3];
    #pragma unroll
    for (int f = 0; f < 3; f++) acc[f] = (floatx4){0.f, 0.f, 0.f, 0.f};

    int xorv = (ln & 7) << 4;

    #pragma unroll
    for (int kf = 0; kf < 8; kf++) {
        int ao = ((16 * wave + ln) * 512 + kf * 64 + q * 16) ^ xorv;
        short8 a = *reinterpret_cast<const short8*>(&Al[ao]);
        int bo0 = (ln * 512 + kf * 64 + q * 16) ^ xorv;
        #pragma unroll
        for (int f = 0; f < 3; f++) {
            short8 bfr = *reinterpret_cast<const short8*>(&Bl[bo0 + f * 8192]);
            acc[f] = __builtin_amdgcn_mfma_f32_16x16x32_bf16(a, bfr, acc[f], 0, 0, 0);
        }
    }

    float a2sv[3], a2dv[3];
    #pragma unroll
    for (int f = 0; f < 3; f++) {
        int c = 16 * f + ln;
        a2sv[f] = (c < OUT_CH) ? a2s[c] : 0.f;
        a2dv[f] = (c < OUT_CH) ? a2d[c] : 0.f;
    }
    #pragma unroll
    for (int r = 0; r < 4; r++) {
        int n = n0 + 16 * wave + q * 4 + r;
        float ps = acc[0][r] * a2sv[0] + acc[1][r] * a2sv[1] + acc[2][r] * a2sv[2];
        float pd = acc[0][r] * a2dv[0] + acc[1][r] * a2dv[1] + acc[2][r] * a2dv[2];
        ps += __shfl_xor(ps, 1); ps += __shfl_xor(ps, 2);
        ps += __shfl_xor(ps, 4); ps += __shfl_xor(ps, 8);
        pd += __shfl_xor(pd, 1); pd += __shfl_xor(pd, 2);
        pd += __shfl_xor(pd, 4); pd += __shfl_xor(pd, 8);
        if (n < N_NODES) {
            #pragma unroll
            for (int f = 0; f < 3; f++) {
                int c = 16 * f + ln;
                if (c < OUT_CH)
                    h3b[(size_t)n * OUT_CH + c] = f2bf(acc[f][r]);
            }
            if (ln == 0) { as2[n] = ps; ad2[n] = pd; }
        }
    }
}

// ---------------- Layer 2 attention + aggregate + log_softmax ----------------

__global__ __launch_bounds__(256) void aggr2(const unsigned short* __restrict__ h3b,
                                             const float* __restrict__ as2,
                                             const float* __restrict__ ad2,
                                             const float* __restrict__ b2,
                                             const int* __restrict__ degv,
                                             const int* __restrict__ csr,
                                             float* __restrict__ out) {
    int d = blockIdx.x * 4 + (threadIdx.x >> 6);
    int lane = threadIdx.x & 63;
    int start = d * CSTRIDE;
    int deg = degv[d];
    deg = (deg > CSTRIDE) ? CSTRIDE : deg;
    float adv = ad2[d];
    bool ok = (lane < OUT_CH);
    int cl = ok ? lane : 0;

    float acc = 0.f, den = 0.f;
    int jj = 0;
    for (; jj + 8 <= deg; jj += 8) {
        int s[8];
        #pragma unroll
        for (int i = 0; i < 8; i++) s[i] = csr[start + jj + i];
        float e[8];
        #pragma unroll
        for (int i = 0; i < 8; i++) e[i] = as2[s[i]];
        unsigned short qv[8];
        #pragma unroll
        for (int i = 0; i < 8; i++) qv[i] = h3b[(size_t)s[i] * OUT_CH + cl];
        #pragma unroll
        for (int i = 0; i < 8; i++) {
            float w = lexp(e[i] + adv);
            den += w;
            acc = fmaf(bf2f(qv[i]), w, acc);
        }
    }
    for (; jj < deg; jj++) {
        int s = csr[start + jj];
        float w = lexp(as2[s] + adv);
        den += w;
        acc = fmaf(bf2f(h3b[(size_t)s * OUT_CH + cl]), w, acc);
    }

    float r = ok ? (acc / (den + 1e-16f) + b2[lane]) : -1e30f;
    float mx = r;
    #pragma unroll
    for (int off = 32; off >= 1; off >>= 1) mx = fmaxf(mx, __shfl_xor(mx, off));
    float ex = ok ? __expf(r - mx) : 0.f;
    float se = ex;
    #pragma unroll
    for (int off = 32; off >= 1; off >>= 1) se += __shfl_xor(se, off);
    if (ok) out[(size_t)d * OUT_CH + lane] = r - mx - __logf(se);
}

// ---------------- host launcher ----------------
// 5 dispatches: setup_prep(+x warm), gemm1(32-row tiles + bucket build),
// aggr1, gemm2, aggr2.

extern "C" void kernel_launch(void* const* d_in, const int* in_sizes, int n_in,
                              void* d_out, int out_size, void* d_ws, size_t ws_size,
                              hipStream_t stream) {
    const float* x   = (const float*)d_in[0];
    const int*   ei  = (const int*)  d_in[1];
    const float* W1  = (const float*)d_in[2];
    const float* a1s = (const float*)d_in[3];
    const float* a1d = (const float*)d_in[4];
    const float* b1  = (const float*)d_in[5];
    const float* W2  = (const float*)d_in[6];
    const float* a2s = (const float*)d_in[7];
    const float* a2d = (const float*)d_in[8];
    const float* b2  = (const float*)d_in[9];
    float* out = (float*)d_out;

    char* p = (char*)d_ws;
    auto alloc = [&](size_t bytes) {
        char* r = p;
        p += (bytes + 255) & ~(size_t)255;
        return r;
    };
    unsigned short* h1b = (unsigned short*)alloc((size_t)N_NODES * HH * 2);
    unsigned short* h2b = (unsigned short*)alloc((size_t)N_PAD * HH * 2);
    unsigned short* h3b = (unsigned short*)alloc((size_t)N_NODES * OUT_CH * 2);
    unsigned short* w1t = (unsigned short*)alloc((size_t)IN_CH * HH * 2);
    unsigned short* w2t = (unsigned short*)alloc((size_t)NC2 * HH * 2);
    float* as1  = (float*)alloc((size_t)N_NODES * HEADS * 4);
    float* ad1  = (float*)alloc((size_t)N_NODES * HEADS * 4);
    float* as2v = (float*)alloc((size_t)N_NODES * 4);
    float* ad2v = (float*)alloc((size_t)N_NODES * 4);
    int* deg    = (int*)alloc((size_t)N_NODES * 4);
    int* csr    = (int*)alloc((size_t)N_NODES * CSTRIDE * 4);

    setup_prep<<<ZB_BLKS + HH + NC2 + XW_BLKS, 256, 0, stream>>>(
        x, W1, W2, w1t, w2t, deg);
    gemm1<<<G1_BLKS + HIST_BLKS, 256, 0, stream>>>(x, w1t, a1s, a1d, h1b, as1, ad1,
                                                   ei, deg, csr);
    aggr1<<<N_NODES / 4, 256, 0, stream>>>(h1b, as1, ad1, b1, deg, csr, h2b);
    gemm2<<<313, 256, 0, stream>>>(h2b, w2t, a2s, a2d, h3b, as2v, ad2v);
    aggr2<<<N_NODES / 4, 256, 0, stream>>>(h3b, as2v, ad2v, b2, deg, csr, out);
}

// Round 13
// 157.162 us; speedup vs baseline: 1.0733x; 1.0264x over previous
//
#include <hip/hip_runtime.h>
#include <math.h>

#define N_NODES 20000
#define E_RAW   320000
#define E_TOT   (E_RAW + N_NODES)
#define IN_CH   256
#define HEADS   8
#define HID     32
#define HH      (HEADS*HID)   // 256
#define OUT_CH  40
#define NC2     48            // OUT_CH padded to 3x16
#define NEG     0.2f
#define CSTRIDE 64            // fixed bucket capacity per dst; P(deg>63) ~ 1e-16

#define ZB_BLKS   79                       // zero deg: 79*256 >= 20000
#define HIST_BLKS ((E_TOT + 255) / 256)    // 1329 (bucket build, in gemm1 tail)
#define G1_BLKS   313                      // ceil(20000/64)
#define N_PAD     20032                    // padded rows for OOB-safe h2b staging

typedef __attribute__((ext_vector_type(8))) short  short8;
typedef __attribute__((ext_vector_type(4))) float  floatx4;

// bf16 helpers (bit-level, round-to-nearest-even; values are finite)
__device__ __forceinline__ unsigned short f2bf(float f) {
    unsigned int u = __float_as_uint(f);
    unsigned int r = (u + 0x7FFFu + ((u >> 16) & 1u)) >> 16;
    return (unsigned short)r;
}
__device__ __forceinline__ float bf2f(unsigned short h) {
    return __uint_as_float(((unsigned int)h) << 16);
}
__device__ __forceinline__ float lexp(float v) {
    v = (v > 0.f) ? v : NEG * v;
    return __expf(v);
}

// async global->LDS, 16B per lane. LDS dest is wave-uniform base + lane*16;
// global src is per-lane (we bake the XOR swizzle into the src address).
__device__ __forceinline__ void gload16(const void* g, void* l) {
    __builtin_amdgcn_global_load_lds(
        (const __attribute__((address_space(1))) void*)g,
        (__attribute__((address_space(3))) void*)l, 16, 0, 0);
}

// ---------------- setup: deg zero + w1t/w2t prepack -------------------------

__global__ void setup_prep(const float* __restrict__ W1,
                           const float* __restrict__ W2,
                           unsigned short* __restrict__ w1t,
                           unsigned short* __restrict__ w2t,
                           int* __restrict__ deg) {
    int b = blockIdx.x;
    int t = threadIdx.x;
    if (b < ZB_BLKS) {
        int i = b * 256 + t;
        if (i < N_NODES) deg[i] = 0;
    } else if (b < ZB_BLKS + HH) {
        int c = b - ZB_BLKS;
        w1t[c * IN_CH + t] = f2bf(W1[(size_t)t * HH + c]);
    } else {
        int c = b - ZB_BLKS - HH;       // 0..47
        w2t[c * HH + t] = (c < OUT_CH) ? f2bf(W2[(size_t)t * OUT_CH + c]) : (unsigned short)0;
    }
}

// ---------------- Layer 1 GEMM + fused single-pass bucket build -------------
// A-DIRECT-TO-REGISTER: each lane preloads its own 8 A-fragments (64 fp32,
// 16 back-to-back dwordx4 -> deep MLP on the cold x read) and converts to
// bf16 in-register. A rows are wave-private (no cross-wave reuse), so LDS
// staging bought nothing. LDS = B-chunk only (32 KiB) -> 5 blocks/CU;
// scatter tail blocks get 20 waves/CU. Accumulation order bit-identical.
__global__ __launch_bounds__(256) void gemm1(const float* __restrict__ x,
                                             const unsigned short* __restrict__ w1t,
                                             const float* __restrict__ a1s,
                                             const float* __restrict__ a1d,
                                             unsigned short* __restrict__ h1b,
                                             float* __restrict__ as1,
                                             float* __restrict__ ad1,
                                             const int* __restrict__ ei,
                                             int* __restrict__ deg,
                                             int* __restrict__ csr) {
    __shared__ unsigned char Bl[256 * 128];   // 32 KiB: [col][128B K-chunk]
    int t = threadIdx.x;

    if (blockIdx.x >= G1_BLKS) {              // fused bucket build (hist+scatter)
        int e = (blockIdx.x - G1_BLKS) * 256 + t;
        if (e < E_TOT) {
            int s, d;
            if (e < E_RAW) { s = ei[e]; d = ei[E_RAW + e]; }
            else           { s = e - E_RAW; d = s; }
            int slot = atomicAdd(&deg[d], 1);
            if (slot < CSTRIDE) csr[d * CSTRIDE + slot] = s;
        }
        return;
    }

    int wave = t >> 6, lane = t & 63;
    int ln = lane & 15, q = lane >> 4;
    int n0 = blockIdx.x * 64;
    const char* bbase = (const char*)w1t;

    // stage B chunk 0 via async DMA first (drains under A preload/convert)
    #pragma unroll
    for (int j = 0; j < 8; j++) {
        int R = (wave * 8 + j) * 1024;
        int o = R + lane * 16;
        int r = o >> 7;
        int cb = (o & 127) ^ ((r & 7) << 4);
        gload16(bbase + (size_t)r * 512 + cb, &Bl[R]);
    }

    // A preload: this lane's row, all 8 fragments (c=0..3, ks=0..1)
    int arow = n0 + 16 * wave + ln;
    bool rok = (arow < N_NODES);
    const float* xrow = &x[(size_t)arow * IN_CH];
    float4 av[16];
    #pragma unroll
    for (int c = 0; c < 4; c++) {
        #pragma unroll
        for (int ks = 0; ks < 2; ks++) {
            int off = c * 64 + ks * 32 + q * 8;
            int idx = (c * 2 + ks) * 2;
            av[idx]     = rok ? *reinterpret_cast<const float4*>(xrow + off)
                              : make_float4(0.f, 0.f, 0.f, 0.f);
            av[idx + 1] = rok ? *reinterpret_cast<const float4*>(xrow + off + 4)
                              : make_float4(0.f, 0.f, 0.f, 0.f);
        }
    }
    short8 afr[8];
    #pragma unroll
    for (int fi = 0; fi < 8; fi++) {
        float4 v0 = av[fi * 2], v1 = av[fi * 2 + 1];
        short8 a;
        a[0] = (short)f2bf(v0.x); a[1] = (short)f2bf(v0.y);
        a[2] = (short)f2bf(v0.z); a[3] = (short)f2bf(v0.w);
        a[4] = (short)f2bf(v1.x); a[5] = (short)f2bf(v1.y);
        a[6] = (short)f2bf(v1.z); a[7] = (short)f2bf(v1.w);
        afr[fi] = a;
    }
    __syncthreads();      // B chunk 0 ready (gload16 drained by barrier)

    floatx4 acc[16];
    #pragma unroll
    for (int f = 0; f < 16; f++) acc[f] = (floatx4){0.f, 0.f, 0.f, 0.f};

    int xorv = (ln & 7) << 4;                 // B-col&7 == ln&7 for all frags

    for (int c = 0; c < 4; c++) {
        #pragma unroll
        for (int ks = 0; ks < 2; ks++) {
            short8 a = afr[c * 2 + ks];
            int bo0 = ln * 128 + ((ks * 64 + q * 16) ^ xorv);
            #pragma unroll
            for (int f = 0; f < 16; f++) {
                short8 bfr = *reinterpret_cast<const short8*>(&Bl[bo0 + f * 2048]);
                acc[f] = __builtin_amdgcn_mfma_f32_16x16x32_bf16(a, bfr, acc[f], 0, 0, 0);
            }
        }
        if (c < 3) {
            __syncthreads();                  // all waves done reading Bl
            #pragma unroll
            for (int j = 0; j < 8; j++) {
                int R = (wave * 8 + j) * 1024;
                int o = R + lane * 16;
                int r = o >> 7;
                int cb = (o & 127) ^ ((r & 7) << 4);
                gload16(bbase + (size_t)r * 512 + (c + 1) * 128 + cb, &Bl[R]);
            }
            __syncthreads();                  // drain + publish new chunk
        }
    }

    float Asr[16], Adr[16];
    #pragma unroll
    for (int f = 0; f < 16; f++) {
        Asr[f] = a1s[16 * f + ln];
        Adr[f] = a1d[16 * f + ln];
    }
    #pragma unroll
    for (int f = 0; f < 16; f++) {
        #pragma unroll
        for (int r = 0; r < 4; r++) {
            int n = n0 + 16 * wave + q * 4 + r;
            if (n < N_NODES)
                h1b[(size_t)n * HH + 16 * f + ln] = f2bf(acc[f][r]);
        }
    }
    #pragma unroll
    for (int lh = 0; lh < 8; lh++) {
        #pragma unroll
        for (int r = 0; r < 4; r++) {
            float ps = acc[2*lh][r] * Asr[2*lh] + acc[2*lh+1][r] * Asr[2*lh+1];
            float pd = acc[2*lh][r] * Adr[2*lh] + acc[2*lh+1][r] * Adr[2*lh+1];
            ps += __shfl_xor(ps, 1); ps += __shfl_xor(ps, 2);
            ps += __shfl_xor(ps, 4); ps += __shfl_xor(ps, 8);
            pd += __shfl_xor(pd, 1); pd += __shfl_xor(pd, 2);
            pd += __shfl_xor(pd, 4); pd += __shfl_xor(pd, 8);
            int n = n0 + 16 * wave + q * 4 + r;
            if (ln == 0 && n < N_NODES) {
                as1[n * HEADS + lh] = ps;
                ad1[n * HEADS + lh] = pd;
            }
        }
    }
}

// ---------------- Layer 1 attention + aggregate + bias + ELU ----------------
// ONE WAVE PER NODE (20000 waves -- gather is latency-bound, needs max TLP).

__global__ __launch_bounds__(256) void aggr1(const unsigned short* __restrict__ h1b,
                                             const float* __restrict__ as1,
                                             const float* __restrict__ ad1,
                                             const float* __restrict__ b1,
                                             const int* __restrict__ degv,
                                             const int* __restrict__ csr,
                                             unsigned short* __restrict__ h2b) {
    int d = blockIdx.x * 4 + (threadIdx.x >> 6);
    int lane = threadIdx.x & 63;
    int h = lane >> 3;
    int c4 = lane * 4;
    int start = d * CSTRIDE;
    int deg = degv[d];
    deg = (deg > CSTRIDE) ? CSTRIDE : deg;
    float adv = ad1[d * HEADS + h];

    float a0 = 0.f, a1 = 0.f, a2 = 0.f, a3 = 0.f, den = 0.f;
    int jj = 0;
    for (; jj + 8 <= deg; jj += 8) {
        int s[8];
        #pragma unroll
        for (int i = 0; i < 8; i++) s[i] = csr[start + jj + i];
        float e[8];
        #pragma unroll
        for (int i = 0; i < 8; i++) e[i] = as1[s[i] * HEADS + h];
        ushort4 pv[8];
        #pragma unroll
        for (int i = 0; i < 8; i++)
            pv[i] = *reinterpret_cast<const ushort4*>(&h1b[(size_t)s[i] * HH + c4]);
        #pragma unroll
        for (int i = 0; i < 8; i++) {
            float w = lexp(e[i] + adv);
            den += w;
            a0 = fmaf(bf2f(pv[i].x), w, a0);
            a1 = fmaf(bf2f(pv[i].y), w, a1);
            a2 = fmaf(bf2f(pv[i].z), w, a2);
            a3 = fmaf(bf2f(pv[i].w), w, a3);
        }
    }
    for (; jj < deg; jj++) {
        int s = csr[start + jj];
        float w = lexp(as1[s * HEADS + h] + adv);
        den += w;
        ushort4 pv = *reinterpret_cast<const ushort4*>(&h1b[(size_t)s * HH + c4]);
        a0 = fmaf(bf2f(pv.x), w, a0);
        a1 = fmaf(bf2f(pv.y), w, a1);
        a2 = fmaf(bf2f(pv.z), w, a2);
        a3 = fmaf(bf2f(pv.w), w, a3);
    }
    float inv = 1.0f / (den + 1e-16f);
    float4 bv = *reinterpret_cast<const float4*>(&b1[c4]);
    float r0 = a0 * inv + bv.x;
    float r1 = a1 * inv + bv.y;
    float r2 = a2 * inv + bv.z;
    float r3 = a3 * inv + bv.w;
    r0 = (r0 > 0.f) ? r0 : (__expf(r0) - 1.f);
    r1 = (r1 > 0.f) ? r1 : (__expf(r1) - 1.f);
    r2 = (r2 > 0.f) ? r2 : (__expf(r2) - 1.f);
    r3 = (r3 > 0.f) ? r3 : (__expf(r3) - 1.f);
    ushort4 ov;
    ov.x = f2bf(r0); ov.y = f2bf(r1); ov.z = f2bf(r2); ov.w = f2bf(r3);
    *reinterpret_cast<ushort4*>(&h2b[(size_t)d * HH + c4]) = ov;
}

// ---------------- Layer 2 GEMM: fully async-LDS staged, single phase --------

__global__ __launch_bounds__(256) void gemm2(const unsigned short* __restrict__ h2b,
                                             const unsigned short* __restrict__ w2t,
                                             const float* __restrict__ a2s,
                                             const float* __restrict__ a2d,
                                             unsigned short* __restrict__ h3b,
                                             float* __restrict__ as2,
                                             float* __restrict__ ad2) {
    __shared__ unsigned char Al[64 * 512];   // 32 KiB
    __shared__ unsigned char Bl[NC2 * 512];  // 24 KiB
    int t = threadIdx.x;
    int wave = t >> 6, lane = t & 63;
    int ln = lane & 15, q = lane >> 4;
    int n0 = blockIdx.x * 64;
    const char* abase = (const char*)h2b + (size_t)n0 * 512;
    const char* bbase = (const char*)w2t;

    #pragma unroll
    for (int j = 0; j < 8; j++) {
        int R = (wave * 8 + j) * 1024;
        int o = R + lane * 16;
        int r = o >> 9;
        int cb = (o & 511) ^ ((r & 7) << 4);
        gload16(abase + (size_t)r * 512 + cb, &Al[R]);
    }
    #pragma unroll
    for (int j = 0; j < 6; j++) {
        int R = (wave * 6 + j) * 1024;
        int o = R + lane * 16;
        int r = o >> 9;
        int cb = (o & 511) ^ ((r & 7) << 4);
        gload16(bbase + (size_t)r * 512 + cb, &Bl[R]);
    }
    __syncthreads();

    floatx4 acc[3];
    #pragma unroll
    for (int f = 0; f < 3; f++) acc[f] = (floatx4){0.f, 0.f, 0.f, 0.f};

    int xorv = (ln & 7) << 4;

    #pragma unroll
    for (int kf = 0; kf < 8; kf++) {
        int ao = ((16 * wave + ln) * 512 + kf * 64 + q * 16) ^ xorv;
        short8 a = *reinterpret_cast<const short8*>(&Al[ao]);
        int bo0 = (ln * 512 + kf * 64 + q * 16) ^ xorv;
        #pragma unroll
        for (int f = 0; f < 3; f++) {
            short8 bfr = *reinterpret_cast<const short8*>(&Bl[bo0 + f * 8192]);
            acc[f] = __builtin_amdgcn_mfma_f32_16x16x32_bf16(a, bfr, acc[f], 0, 0, 0);
        }
    }

    float a2sv[3], a2dv[3];
    #pragma unroll
    for (int f = 0; f < 3; f++) {
        int c = 16 * f + ln;
        a2sv[f] = (c < OUT_CH) ? a2s[c] : 0.f;
        a2dv[f] = (c < OUT_CH) ? a2d[c] : 0.f;
    }
    #pragma unroll
    for (int r = 0; r < 4; r++) {
        int n = n0 + 16 * wave + q * 4 + r;
        float ps = acc[0][r] * a2sv[0] + acc[1][r] * a2sv[1] + acc[2][r] * a2sv[2];
        float pd = acc[0][r] * a2dv[0] + acc[1][r] * a2dv[1] + acc[2][r] * a2dv[2];
        ps += __shfl_xor(ps, 1); ps += __shfl_xor(ps, 2);
        ps += __shfl_xor(ps, 4); ps += __shfl_xor(ps, 8);
        pd += __shfl_xor(pd, 1); pd += __shfl_xor(pd, 2);
        pd += __shfl_xor(pd, 4); pd += __shfl_xor(pd, 8);
        if (n < N_NODES) {
            #pragma unroll
            for (int f = 0; f < 3; f++) {
                int c = 16 * f + ln;
                if (c < OUT_CH)
                    h3b[(size_t)n * OUT_CH + c] = f2bf(acc[f][r]);
            }
            if (ln == 0) { as2[n] = ps; ad2[n] = pd; }
        }
    }
}

// ---------------- Layer 2 attention + aggregate + log_softmax ----------------

__global__ __launch_bounds__(256) void aggr2(const unsigned short* __restrict__ h3b,
                                             const float* __restrict__ as2,
                                             const float* __restrict__ ad2,
                                             const float* __restrict__ b2,
                                             const int* __restrict__ degv,
                                             const int* __restrict__ csr,
                                             float* __restrict__ out) {
    int d = blockIdx.x * 4 + (threadIdx.x >> 6);
    int lane = threadIdx.x & 63;
    int start = d * CSTRIDE;
    int deg = degv[d];
    deg = (deg > CSTRIDE) ? CSTRIDE : deg;
    float adv = ad2[d];
    bool ok = (lane < OUT_CH);
    int cl = ok ? lane : 0;

    float acc = 0.f, den = 0.f;
    int jj = 0;
    for (; jj + 8 <= deg; jj += 8) {
        int s[8];
        #pragma unroll
        for (int i = 0; i < 8; i++) s[i] = csr[start + jj + i];
        float e[8];
        #pragma unroll
        for (int i = 0; i < 8; i++) e[i] = as2[s[i]];
        unsigned short qv[8];
        #pragma unroll
        for (int i = 0; i < 8; i++) qv[i] = h3b[(size_t)s[i] * OUT_CH + cl];
        #pragma unroll
        for (int i = 0; i < 8; i++) {
            float w = lexp(e[i] + adv);
            den += w;
            acc = fmaf(bf2f(qv[i]), w, acc);
        }
    }
    for (; jj < deg; jj++) {
        int s = csr[start + jj];
        float w = lexp(as2[s] + adv);
        den += w;
        acc = fmaf(bf2f(h3b[(size_t)s * OUT_CH + cl]), w, acc);
    }

    float r = ok ? (acc / (den + 1e-16f) + b2[lane]) : -1e30f;
    float mx = r;
    #pragma unroll
    for (int off = 32; off >= 1; off >>= 1) mx = fmaxf(mx, __shfl_xor(mx, off));
    float ex = ok ? __expf(r - mx) : 0.f;
    float se = ex;
    #pragma unroll
    for (int off = 32; off >= 1; off >>= 1) se += __shfl_xor(se, off);
    if (ok) out[(size_t)d * OUT_CH + lane] = r - mx - __logf(se);
}

// ---------------- host launcher ----------------
// 5 dispatches: setup_prep, gemm1(A-in-reg + bucket build), aggr1, gemm2, aggr2.

extern "C" void kernel_launch(void* const* d_in, const int* in_sizes, int n_in,
                              void* d_out, int out_size, void* d_ws, size_t ws_size,
                              hipStream_t stream) {
    const float* x   = (const float*)d_in[0];
    const int*   ei  = (const int*)  d_in[1];
    const float* W1  = (const float*)d_in[2];
    const float* a1s = (const float*)d_in[3];
    const float* a1d = (const float*)d_in[4];
    const float* b1  = (const float*)d_in[5];
    const float* W2  = (const float*)d_in[6];
    const float* a2s = (const float*)d_in[7];
    const float* a2d = (const float*)d_in[8];
    const float* b2  = (const float*)d_in[9];
    float* out = (float*)d_out;

    char* p = (char*)d_ws;
    auto alloc = [&](size_t bytes) {
        char* r = p;
        p += (bytes + 255) & ~(size_t)255;
        return r;
    };
    unsigned short* h1b = (unsigned short*)alloc((size_t)N_NODES * HH * 2);
    unsigned short* h2b = (unsigned short*)alloc((size_t)N_PAD * HH * 2);
    unsigned short* h3b = (unsigned short*)alloc((size_t)N_NODES * OUT_CH * 2);
    unsigned short* w1t = (unsigned short*)alloc((size_t)IN_CH * HH * 2);
    unsigned short* w2t = (unsigned short*)alloc((size_t)NC2 * HH * 2);
    float* as1  = (float*)alloc((size_t)N_NODES * HEADS * 4);
    float* ad1  = (float*)alloc((size_t)N_NODES * HEADS * 4);
    float* as2v = (float*)alloc((size_t)N_NODES * 4);
    float* ad2v = (float*)alloc((size_t)N_NODES * 4);
    int* deg    = (int*)alloc((size_t)N_NODES * 4);
    int* csr    = (int*)alloc((size_t)N_NODES * CSTRIDE * 4);

    setup_prep<<<ZB_BLKS + HH + NC2, 256, 0, stream>>>(W1, W2, w1t, w2t, deg);
    gemm1<<<G1_BLKS + HIST_BLKS, 256, 0, stream>>>(x, w1t, a1s, a1d, h1b, as1, ad1,
                                                   ei, deg, csr);
    aggr1<<<N_NODES / 4, 256, 0, stream>>>(h1b, as1, ad1, b1, deg, csr, h2b);
    gemm2<<<313, 256, 0, stream>>>(h2b, w2t, a2s, a2d, h3b, as2v, ad2v);
    aggr2<<<N_NODES / 4, 256, 0, stream>>>(h3b, as2v, ad2v, b2, deg, csr, out);
}